// Round 11
// baseline (973.560 us; speedup 1.0000x reference)
//
#include <hip/hip_runtime.h>
#include <hip/hip_bf16.h>

// ReEig = 0.5*(X + eps*I + |X - eps*I|);  |B| = B*sign(B);  sign via Newton-Schulz,
// symmetrization folded into MFMA double products (X <- XW' + W'X, W'=W/2).
// r10 = r8's PROVEN numerics (absmax 0.047) + r9's half-plane LDS structure
// (9216 B/wave -> 3 blocks/CU). r9 post-mortem: moving the 1-pass bf16 window
// earlier (it-3) let 1-pass Gram noise (~0.03 spectral) randomize signs of
// eigenvalues up to ~0.1 -> absmax 0.1875. Here: 10 grow + 5 polish, 1-pass
// only in [6,13), double product EVERYWHERE, mu-scaling at it-1 via the
// monotone bound f(min(mu,2/3)), validation tight @0.015. fp32 fallback net.

typedef float  f32x4  __attribute__((ext_vector_type(4)));
typedef short  short8 __attribute__((ext_vector_type(8)));

constexpr float EPS_  = 1e-4f;
constexpr int   ITERS = 15;   // 0-9 grow (2.25x), 10-14 polish (1.5x)
constexpr int   GROW  = 10;
constexpr int   ONE_LO = 6, ONE_HI = 13;  // 1-pass bf16 window
constexpr int   LDF   = 36;   // half-plane fp32 row stride (floats)
constexpr int   LDH   = 40;   // half-plane bf16 row stride (shorts)
constexpr int   WAVE_F = 64 * LDF;   // 9216 B per wave

struct Frag { short8 hi, lo; };

__device__ __forceinline__ void lds_fence() {
    asm volatile("s_waitcnt lgkmcnt(0)" ::: "memory");
    __builtin_amdgcn_sched_barrier(0);
}
__device__ __forceinline__ unsigned short bf_hi(float x) {
    return __builtin_bit_cast(unsigned short, __float2bfloat16(x));  // RNE
}
__device__ __forceinline__ float bf_f(unsigned short h) {
    return __uint_as_float((unsigned)h << 16);
}
__device__ __forceinline__ Frag pack3(const float e[8]) {
    Frag f;
#pragma unroll
    for (int j = 0; j < 8; ++j) {
        const unsigned short h = bf_hi(e[j]);
        f.hi[j] = (short)h;
        f.lo[j] = (short)bf_hi(e[j] - bf_f(h));   // exact residual (Dekker)
    }
    return f;
}
__device__ __forceinline__ f32x4 mfma_bf(short8 a, short8 b, f32x4 c) {
    return __builtin_amdgcn_mfma_f32_16x16x32_bf16(a, b, c, 0, 0, 0);
}
__device__ __forceinline__ f32x4 mfma3(const Frag& a, const Frag& b, f32x4 c) {
    c = mfma_bf(a.hi, b.hi, c);
    c = mfma_bf(a.hi, b.lo, c);
    c = mfma_bf(a.lo, b.hi, c);
    return c;
}

// ---- half-plane staging, swizzle col ^= row&24 ----
__device__ __forceinline__ void stT3(float* P, int c, int h4, int iL, int j, f32x4 v) {
    const int row = 16 * j + c;
    const int col = (16 * iL + 4 * h4) ^ (row & 24);
    *reinterpret_cast<f32x4*>(P + row * LDF + col) = v;
}
__device__ __forceinline__ void stT1(short* H, int c, int h4, int iL, int j, f32x4 v) {
    const int row = 16 * j + c;
    const int col = (16 * iL + 4 * h4) ^ (row & 24);
    uint2 u;
    u.x = ((unsigned)bf_hi(v[1]) << 16) | bf_hi(v[0]);
    u.y = ((unsigned)bf_hi(v[3]) << 16) | bf_hi(v[2]);
    *reinterpret_cast<uint2*>(H + row * LDH + col) = u;
}
__device__ __forceinline__ void rd3row(const float* P, int c, int h4, int t, float e[8]) {
    const int row = 16 * t + c;
    const int b0  = (8 * h4) ^ (row & 24);
    const float* rp = P + row * LDF + b0;
    const f32x4 a = *reinterpret_cast<const f32x4*>(rp);
    const f32x4 b = *reinterpret_cast<const f32x4*>(rp + 4);
    e[0]=a[0]; e[1]=a[1]; e[2]=a[2]; e[3]=a[3];
    e[4]=b[0]; e[5]=b[1]; e[6]=b[2]; e[7]=b[3];
}
__device__ __forceinline__ short8 rd1row(const short* H, int c, int h4, int t) {
    const int row = 16 * t + c;
    const int b0  = (8 * h4) ^ (row & 24);
    return *reinterpret_cast<const short8*>(H + row * LDH + b0);
}
__device__ __forceinline__ void load_row8(const float* src, int c, int h4,
                                          int t, int S, float e[8]) {
    const int row = 16 * t + c;
    const float* rp = src + row * 64 + 32 * S + 8 * h4;
    const float4 a = *reinterpret_cast<const float4*>(rp);
    const float4 b = *reinterpret_cast<const float4*>(rp + 4);
    e[0]=a.x; e[1]=a.y; e[2]=a.z; e[3]=a.w;
    e[4]=b.x; e[5]=b.y; e[6]=b.z; e[7]=b.w;
    const int dj = row - (32 * S + 8 * h4);
#pragma unroll
    for (int j = 0; j < 8; ++j) if (j == dj) e[j] -= EPS_;
}
__device__ __forceinline__ void zeroD(f32x4 Z[4][4]) {
#pragma unroll
    for (int i = 0; i < 4; ++i)
#pragma unroll
    for (int j = 0; j < 4; ++j) Z[i][j] = f32x4{0.f, 0.f, 0.f, 0.f};
}

__global__ __launch_bounds__(256, 3) void reeig_mx(const float* __restrict__ in,
                                                   float* __restrict__ out,
                                                   int* __restrict__ flags) {
    __shared__ __align__(16) float lds4[4 * WAVE_F];   // 36864 B/block

    const int lane = threadIdx.x & 63;
    const int wave = threadIdx.x >> 6;
    const int c    = lane & 15;
    const int h4   = lane >> 4;
    float* P = &lds4[wave * WAVE_F];
    short* H = reinterpret_cast<short*>(P);

    const long mat = (long)blockIdx.x * 4 + wave;
    const float* __restrict__ src = in  + mat * 4096;
    float*       __restrict__ dst = out + mat * 4096;

    // ---- load B = X - eps*I as UNSCALED frags; Frobenius norm ----
    Frag xf[2][4];
    float fro = 0.f;
#pragma unroll
    for (int S = 0; S < 2; ++S)
#pragma unroll
    for (int t = 0; t < 4; ++t) {
        float e[8];
        load_row8(src, c, h4, t, S, e);
#pragma unroll
        for (int j = 0; j < 8; ++j) fro = fmaf(e[j], e[j], fro);
        xf[S][t] = pack3(e);
    }
#pragma unroll
    for (int m = 1; m < 64; m <<= 1) fro += __shfl_xor(fro, m, 64);
    const float invF = rsqrtf(fro);

    float s_acc = 0.f;   // ||B^2||_F^2 collected at it 0 -> mu for it 1
    f32x4 Z[4][4];

    for (int it = 0; it < ITERS; ++it) {
        const bool three = (it < ONE_LO) || (it >= ONE_HI);
        float c1 = (it < GROW) ? 2.25f    : 1.5f;
        float c3 = (it < GROW) ? -1.6875f : -0.5f;
        if (it == 0) { c1 *= invF; c3 *= invF * invF * invF; }  // Frobenius fold
        if (it == 1) {
            // mu-scaling: lam_max(X1) <= f(min(mu,2/3)), f(x)=2.25x-1.6875x^3
            float s = s_acc;
#pragma unroll
            for (int m = 1; m < 64; m <<= 1) s += __shfl_xor(s, m, 64);
            const float mu = sqrtf(sqrtf(s)) * invF;   // (sum lam_hat^4)^(1/4)
            const float xm = fminf(mu, 0.6666667f);
            const float fv = 2.25f * xm - 1.6875f * xm * xm * xm;
            const float im = 0.98f / fv;
            c1 *= im; c3 *= im * im * im;
        }
        c1 *= 0.5f; c3 *= 0.5f;   // W' = W/2 for the symmetrized double product

        zeroD(Z);
        f32x4 DH[2][4];

#pragma unroll
        for (int half = 0; half < 2; ++half) {
            const int ib = 2 * half;   // global tile rows ib, ib+1
            // gram half: DH[i2][:] = (X^2) tiles (ib+i2, j)
#pragma unroll
            for (int i2 = 0; i2 < 2; ++i2)
#pragma unroll
            for (int j = 0; j < 4; ++j) DH[i2][j] = f32x4{0.f, 0.f, 0.f, 0.f};
#pragma unroll
            for (int S = 0; S < 2; ++S)
#pragma unroll
            for (int i2 = 0; i2 < 2; ++i2)
#pragma unroll
            for (int j = 0; j < 4; ++j) {
                if (three) DH[i2][j] = mfma3 (xf[S][ib + i2],    xf[S][j],    DH[i2][j]);
                else       DH[i2][j] = mfma_bf(xf[S][ib + i2].hi, xf[S][j].hi, DH[i2][j]);
            }
            if (it == 0) {
#pragma unroll
                for (int i2 = 0; i2 < 2; ++i2)
#pragma unroll
                for (int j = 0; j < 4; ++j)
#pragma unroll
                for (int r = 0; r < 4; ++r) s_acc = fmaf(DH[i2][j][r], DH[i2][j][r], s_acc);
            }
            lds_fence();   // WAR: prior reads of this half retired
            // store W' half (tiles ib+i2, all j), transposed (== W' by symmetry)
#pragma unroll
            for (int i2 = 0; i2 < 2; ++i2)
#pragma unroll
            for (int j = 0; j < 4; ++j) {
                f32x4 v;
#pragma unroll
                for (int r = 0; r < 4; ++r) {
                    v[r] = c3 * DH[i2][j][r];
                    if (ib + i2 == j && c == 4 * h4 + r) v[r] += c1;
                }
                if (three) stT3(P, c, h4, i2, j, v);
                else       stT1(H, c, h4, i2, j, v);
            }
            lds_fence();   // RAW
            // read W' frags for k-block S=half; accumulate BOTH products
            if (three) {
                Frag wf[4];
#pragma unroll
                for (int t = 0; t < 4; ++t) {
                    float e[8]; rd3row(P, c, h4, t, e); wf[t] = pack3(e);
                }
#pragma unroll
                for (int i = 0; i < 4; ++i)
#pragma unroll
                for (int j = 0; j < 4; ++j) {
                    Z[i][j] = mfma3(xf[half][i], wf[j], Z[i][j]);
                    Z[i][j] = mfma3(wf[i], xf[half][j], Z[i][j]);
                }
            } else {
                short8 wh[4];
#pragma unroll
                for (int t = 0; t < 4; ++t) wh[t] = rd1row(H, c, h4, t);
#pragma unroll
                for (int i = 0; i < 4; ++i)
#pragma unroll
                for (int j = 0; j < 4; ++j) {
                    Z[i][j] = mfma_bf(xf[half][i].hi, wh[j], Z[i][j]);
                    Z[i][j] = mfma_bf(wh[i], xf[half][j].hi, Z[i][j]);
                }
            }
        }

        // ---- X_new staging: store Z halves transposed, read back frags ----
#pragma unroll
        for (int half = 0; half < 2; ++half) {
            const int ib = 2 * half;
            lds_fence();   // WAR: previous reads retired
#pragma unroll
            for (int i2 = 0; i2 < 2; ++i2)
#pragma unroll
            for (int j = 0; j < 4; ++j) {
                if (three) stT3(P, c, h4, i2, j, Z[ib + i2][j]);
                else       stT1(H, c, h4, i2, j, Z[ib + i2][j]);
            }
            lds_fence();   // RAW
#pragma unroll
            for (int t = 0; t < 4; ++t) {
                if (three) {
                    float e[8]; rd3row(P, c, h4, t, e); xf[half][t] = pack3(e);
                } else {
                    xf[half][t].hi = rd1row(H, c, h4, t);
                    xf[half][t].lo = short8{0,0,0,0,0,0,0,0};
                }
            }
        }
    }
    // xf = frags of S = sign(B)

    // validation: S^2 ~ I elementwise @0.015 (r8's proven tightness)
    bool bad = false;
    zeroD(Z);
#pragma unroll
    for (int S = 0; S < 2; ++S)
#pragma unroll
    for (int i = 0; i < 4; ++i)
#pragma unroll
    for (int j = 0; j < 4; ++j) Z[i][j] = mfma3(xf[S][i], xf[S][j], Z[i][j]);
#pragma unroll
    for (int i = 0; i < 4; ++i)
#pragma unroll
    for (int j = 0; j < 4; ++j)
#pragma unroll
    for (int r = 0; r < 4; ++r) {
        const float expect = (i == j && c == 4 * h4 + r) ? 1.f : 0.f;
        bad |= fabsf(Z[i][j][r] - expect) > 0.015f;
    }

    // epilogue: Z = B*S + S*B (symmetrized double product)
    zeroD(Z);
#pragma unroll
    for (int S = 0; S < 2; ++S) {
        Frag b4[4];
#pragma unroll
        for (int t = 0; t < 4; ++t) {
            float e[8]; load_row8(src, c, h4, t, S, e); b4[t] = pack3(e);
        }
#pragma unroll
        for (int i = 0; i < 4; ++i)
#pragma unroll
        for (int j = 0; j < 4; ++j) {
            Z[i][j] = mfma3(b4[i], xf[S][j], Z[i][j]);
            Z[i][j] = mfma3(xf[S][i], b4[j], Z[i][j]);
        }
    }

    // out = 0.25*(BS+SB) + 0.5*B + eps*I
#pragma unroll
    for (int i = 0; i < 4; ++i)
#pragma unroll
    for (int j = 0; j < 4; ++j)
#pragma unroll
    for (int r = 0; r < 4; ++r) {
        const int p = 16 * i + 4 * h4 + r;
        const int q = 16 * j + c;
        const float bval = src[p * 64 + q] - ((p == q) ? EPS_ : 0.f);
        dst[p * 64 + q] = 0.25f * Z[i][j][r] + 0.5f * bval + ((p == q) ? EPS_ : 0.f);
    }

    const unsigned long long bb = __ballot(bad);
    if (lane == 0) flags[mat] = (bb != 0ull) ? 1 : 0;
}

// ------------------------ fp32 fallback (known good) ------------------------
constexpr int FB_LD = 68;

__device__ __forceinline__ void fb_mm64(const float* __restrict__ A,
                                        const float* __restrict__ Bm,
                                        int ti, int tj, float acc[4][4]) {
#pragma unroll
    for (int r = 0; r < 4; ++r)
#pragma unroll
        for (int cc = 0; cc < 4; ++cc) acc[r][cc] = 0.f;
#pragma unroll 4
    for (int k = 0; k < 64; ++k) {
        const float4 a = *reinterpret_cast<const float4*>(&A [k * FB_LD + 4 * ti]);
        const float4 b = *reinterpret_cast<const float4*>(&Bm[k * FB_LD + 4 * tj]);
        const float ar[4] = {a.x, a.y, a.z, a.w};
        const float br[4] = {b.x, b.y, b.z, b.w};
#pragma unroll
        for (int r = 0; r < 4; ++r)
#pragma unroll
            for (int cc = 0; cc < 4; ++cc)
                acc[r][cc] = fmaf(ar[r], br[cc], acc[r][cc]);
    }
}

__global__ __launch_bounds__(256) void reeig_fb(const float* __restrict__ in,
                                                float* __restrict__ out,
                                                const int* __restrict__ flags) {
    if (flags && flags[blockIdx.x] == 0) return;

    __shared__ __align__(16) float Bs[64 * FB_LD];
    __shared__ __align__(16) float Xs[64 * FB_LD];
    __shared__ __align__(16) float Ws[64 * FB_LD];
    __shared__ float red[4];

    const int tid = threadIdx.x;
    const int tj  = tid & 15;
    const int ti  = tid >> 4;
    const size_t base = (size_t)blockIdx.x * 4096;
    const float* __restrict__ src = in + base;
    float* __restrict__ dst = out + base;

    float4 v4[4];
    float frob = 0.f;
#pragma unroll
    for (int q = 0; q < 4; ++q) {
        const int idx4 = tid + 256 * q;
        const int lin  = idx4 << 2;
        const int r    = lin >> 6;
        const int c    = lin & 63;
        float4 v = reinterpret_cast<const float4*>(src)[idx4];
        const int d = r - c;
        v.x -= (d == 0) ? EPS_ : 0.f;
        v.y -= (d == 1) ? EPS_ : 0.f;
        v.z -= (d == 2) ? EPS_ : 0.f;
        v.w -= (d == 3) ? EPS_ : 0.f;
        v4[q] = v;
        frob += v.x * v.x + v.y * v.y + v.z * v.z + v.w * v.w;
        *reinterpret_cast<float4*>(&Bs[r * FB_LD + c]) = v;
    }
#pragma unroll
    for (int off = 32; off > 0; off >>= 1) frob += __shfl_down(frob, off);
    if ((tid & 63) == 0) red[tid >> 6] = frob;
    __syncthreads();
    const float tot = red[0] + red[1] + red[2] + red[3];
    const float inv = (tot > 0.f) ? rsqrtf(tot) : 0.f;

#pragma unroll
    for (int q = 0; q < 4; ++q) {
        const int idx4 = tid + 256 * q;
        const int lin  = idx4 << 2;
        const int r    = lin >> 6;
        const int c    = lin & 63;
        float4 v = v4[q];
        v.x *= inv; v.y *= inv; v.z *= inv; v.w *= inv;
        *reinterpret_cast<float4*>(&Xs[r * FB_LD + c]) = v;
    }
    __syncthreads();

    float acc[4][4];
    for (int it = 0; it < 14; ++it) {
        const bool  g  = (it < 9);
        const float c1 = g ? 2.25f    : 1.5f;
        const float c3 = g ? -1.6875f : -0.5f;

        fb_mm64(Xs, Xs, ti, tj, acc);
#pragma unroll
        for (int r = 0; r < 4; ++r) {
            const int i = 4 * ti + r;
            float4 w;
            w.x = c3 * acc[r][0] + ((i == 4 * tj + 0) ? c1 : 0.f);
            w.y = c3 * acc[r][1] + ((i == 4 * tj + 1) ? c1 : 0.f);
            w.z = c3 * acc[r][2] + ((i == 4 * tj + 2) ? c1 : 0.f);
            w.w = c3 * acc[r][3] + ((i == 4 * tj + 3) ? c1 : 0.f);
            *reinterpret_cast<float4*>(&Ws[i * FB_LD + 4 * tj]) = w;
        }
        __syncthreads();

        fb_mm64(Xs, Ws, ti, tj, acc);
        __syncthreads();
#pragma unroll
        for (int r = 0; r < 4; ++r) {
            const int i = 4 * ti + r;
            float4 x;
            x.x = acc[r][0]; x.y = acc[r][1]; x.z = acc[r][2]; x.w = acc[r][3];
            *reinterpret_cast<float4*>(&Xs[i * FB_LD + 4 * tj]) = x;
        }
        __syncthreads();
    }

    fb_mm64(Bs, Xs, ti, tj, acc);
#pragma unroll
    for (int r = 0; r < 4; ++r) {
        const int i = 4 * ti + r;
        float4 o;
        o.x = 0.5f * (acc[r][0] + Bs[i * FB_LD + 4 * tj + 0]) + ((i == 4 * tj + 0) ? EPS_ : 0.f);
        o.y = 0.5f * (acc[r][1] + Bs[i * FB_LD + 4 * tj + 1]) + ((i == 4 * tj + 1) ? EPS_ : 0.f);
        o.z = 0.5f * (acc[r][2] + Bs[i * FB_LD + 4 * tj + 2]) + ((i == 4 * tj + 2) ? EPS_ : 0.f);
        o.w = 0.5f * (acc[r][3] + Bs[i * FB_LD + 4 * tj + 3]) + ((i == 4 * tj + 3) ? EPS_ : 0.f);
        *reinterpret_cast<float4*>(&dst[i * 64 + 4 * tj]) = o;
    }
}

extern "C" void kernel_launch(void* const* d_in, const int* in_sizes, int n_in,
                              void* d_out, int out_size, void* d_ws, size_t ws_size,
                              hipStream_t stream) {
    const float* X = (const float*)d_in[0];
    float* O = (float*)d_out;
    const int nmat = in_sizes[0] / 4096;   // 8192
    if (ws_size >= (size_t)nmat * sizeof(int)) {
        int* flags = (int*)d_ws;
        reeig_mx<<<nmat / 4, 256, 0, stream>>>(X, O, flags);
        reeig_fb<<<nmat, 256, 0, stream>>>(X, O, flags);
    } else {
        reeig_fb<<<nmat, 256, 0, stream>>>(X, O, nullptr);
    }
}

// Round 12
// 527.587 us; speedup vs baseline: 1.8453x; 1.8453x over previous
//
#include <hip/hip_runtime.h>
#include <hip/hip_bf16.h>

// ReEig = 0.5*(X + eps*I + |X - eps*I|);  |B| = B*sign(B);  sign via Newton-Schulz,
// symmetrization folded into MFMA double products (X <- XW' + W'X, W'=W/2).
// r11 = r8's full-plane single-accumulator structure (no spills, (256,2)) +
// r10's proven numerics (15 iters, mu at it-1, 1-pass window [6,13)) +
// NEW: staging as separate bf16 hi/lo LDS planes -- split once at store,
// frag reads are direct b128->short8 (no per-read Dekker pack). Bit-identical
// numerics to r10 (absmax 0.047). Validation @0.015 + fp32 fallback retained.

typedef float  f32x4  __attribute__((ext_vector_type(4)));
typedef short  short8 __attribute__((ext_vector_type(8)));

constexpr float EPS_  = 1e-4f;
constexpr int   ITERS = 15;   // 0-9 grow (2.25x), 10-14 polish (1.5x)
constexpr int   GROW  = 10;
constexpr int   ONE_LO = 6, ONE_HI = 13;  // 1-pass bf16 window
constexpr int   LDH   = 72;               // bf16 plane row stride (shorts)
constexpr int   PLANE = 64 * LDH;         // 4608 shorts = 9216 B per plane
constexpr int   WAVE_S = 2 * PLANE;       // hi + lo planes per wave

struct Frag { short8 hi, lo; };

__device__ __forceinline__ void lds_fence() {
    asm volatile("s_waitcnt lgkmcnt(0)" ::: "memory");
    __builtin_amdgcn_sched_barrier(0);
}
__device__ __forceinline__ unsigned short bf_hi(float x) {
    return __builtin_bit_cast(unsigned short, __float2bfloat16(x));  // RNE
}
__device__ __forceinline__ float bf_f(unsigned short h) {
    return __uint_as_float((unsigned)h << 16);
}
__device__ __forceinline__ Frag pack3(const float e[8]) {
    Frag f;
#pragma unroll
    for (int j = 0; j < 8; ++j) {
        const unsigned short h = bf_hi(e[j]);
        f.hi[j] = (short)h;
        f.lo[j] = (short)bf_hi(e[j] - bf_f(h));   // exact residual (Dekker)
    }
    return f;
}
__device__ __forceinline__ f32x4 mfma_bf(short8 a, short8 b, f32x4 c) {
    return __builtin_amdgcn_mfma_f32_16x16x32_bf16(a, b, c, 0, 0, 0);
}
__device__ __forceinline__ f32x4 mfma3(const Frag& a, const Frag& b, f32x4 c) {
    c = mfma_bf(a.hi, b.hi, c);
    c = mfma_bf(a.hi, b.lo, c);
    c = mfma_bf(a.lo, b.hi, c);
    return c;
}

// ---- bf16 hi/lo plane staging, swizzle col ^= row&24 (8-short granules) ----
// transposed store of D-tile (i,j): element (16i+4h4+r, 16j+c) -> plane[16j+c][16i+4h4+r]
__device__ __forceinline__ void stHL(short* Hhi, short* Hlo, bool lo,
                                     int c, int h4, int i, int j, f32x4 v) {
    const int row = 16 * j + c;
    const int col = (16 * i + 4 * h4) ^ (row & 24);
    const int idx = row * LDH + col;
    unsigned short h0 = bf_hi(v[0]), h1 = bf_hi(v[1]), h2 = bf_hi(v[2]), h3 = bf_hi(v[3]);
    uint2 u;
    u.x = ((unsigned)h1 << 16) | h0;
    u.y = ((unsigned)h3 << 16) | h2;
    *reinterpret_cast<uint2*>(Hhi + idx) = u;
    if (lo) {
        unsigned short l0 = bf_hi(v[0] - bf_f(h0)), l1 = bf_hi(v[1] - bf_f(h1));
        unsigned short l2 = bf_hi(v[2] - bf_f(h2)), l3 = bf_hi(v[3] - bf_f(h3));
        uint2 w;
        w.x = ((unsigned)l1 << 16) | l0;
        w.y = ((unsigned)l3 << 16) | l2;
        *reinterpret_cast<uint2*>(Hlo + idx) = w;
    }
}
// frag read: M[16t+c][32S+8h4+j], j=0..7 -> one b128 per plane
__device__ __forceinline__ short8 rdP(const short* H, int c, int h4, int t, int S) {
    const int row = 16 * t + c;
    const int col = (32 * S + 8 * h4) ^ (row & 24);
    return *reinterpret_cast<const short8*>(H + row * LDH + col);
}
__device__ __forceinline__ void load_row8(const float* src, int c, int h4,
                                          int t, int S, float e[8]) {
    const int row = 16 * t + c;
    const float* rp = src + row * 64 + 32 * S + 8 * h4;
    const float4 a = *reinterpret_cast<const float4*>(rp);
    const float4 b = *reinterpret_cast<const float4*>(rp + 4);
    e[0]=a.x; e[1]=a.y; e[2]=a.z; e[3]=a.w;
    e[4]=b.x; e[5]=b.y; e[6]=b.z; e[7]=b.w;
    const int dj = row - (32 * S + 8 * h4);
#pragma unroll
    for (int j = 0; j < 8; ++j) if (j == dj) e[j] -= EPS_;
}
__device__ __forceinline__ void zeroD(f32x4 D[4][4]) {
#pragma unroll
    for (int i = 0; i < 4; ++i)
#pragma unroll
    for (int j = 0; j < 4; ++j) D[i][j] = f32x4{0.f, 0.f, 0.f, 0.f};
}

__global__ __launch_bounds__(256, 2) void reeig_mx(const float* __restrict__ in,
                                                   float* __restrict__ out,
                                                   int* __restrict__ flags) {
    __shared__ __align__(16) short lds4[4 * WAVE_S];   // 73728 B/block

    const int lane = threadIdx.x & 63;
    const int wave = threadIdx.x >> 6;
    const int c    = lane & 15;
    const int h4   = lane >> 4;
    short* Hhi = &lds4[wave * WAVE_S];
    short* Hlo = Hhi + PLANE;

    const long mat = (long)blockIdx.x * 4 + wave;
    const float* __restrict__ src = in  + mat * 4096;
    float*       __restrict__ dst = out + mat * 4096;

    // ---- load B = X - eps*I as UNSCALED frags; Frobenius norm ----
    Frag xf[2][4];
    float fro = 0.f;
#pragma unroll
    for (int S = 0; S < 2; ++S)
#pragma unroll
    for (int t = 0; t < 4; ++t) {
        float e[8];
        load_row8(src, c, h4, t, S, e);
#pragma unroll
        for (int j = 0; j < 8; ++j) fro = fmaf(e[j], e[j], fro);
        xf[S][t] = pack3(e);
    }
#pragma unroll
    for (int m = 1; m < 64; m <<= 1) fro += __shfl_xor(fro, m, 64);
    const float invF = rsqrtf(fro);

    float s_acc = 0.f;   // ||B^2||_F^2 from it-0 gram -> mu at it-1
    f32x4 D[4][4];

    for (int it = 0; it < ITERS; ++it) {
        const bool three = (it < ONE_LO) || (it >= ONE_HI);
        float c1 = (it < GROW) ? 2.25f    : 1.5f;
        float c3 = (it < GROW) ? -1.6875f : -0.5f;
        if (it == 0) { c1 *= invF; c3 *= invF * invF * invF; }  // Frobenius fold
        if (it == 1) {
            // mu-scaling: lam_max(X1) <= f(min(mu,2/3)), f(x)=2.25x-1.6875x^3
            float s = s_acc;
#pragma unroll
            for (int m = 1; m < 64; m <<= 1) s += __shfl_xor(s, m, 64);
            const float mu = sqrtf(sqrtf(s)) * invF;
            const float xm = fminf(mu, 0.6666667f);
            const float fv = 2.25f * xm - 1.6875f * xm * xm * xm;
            const float im = 0.98f / fv;
            c1 *= im; c3 *= im * im * im;
        }
        c1 *= 0.5f; c3 *= 0.5f;   // W' = W/2 for the symmetrized double product

        // ---- gram: D = X^2 (exactly symmetric) ----
        zeroD(D);
#pragma unroll
        for (int S = 0; S < 2; ++S)
#pragma unroll
        for (int i = 0; i < 4; ++i)
#pragma unroll
        for (int j = 0; j < 4; ++j) {
            if (three) D[i][j] = mfma3 (xf[S][i],    xf[S][j],    D[i][j]);
            else       D[i][j] = mfma_bf(xf[S][i].hi, xf[S][j].hi, D[i][j]);
        }
        if (it == 0) {
#pragma unroll
            for (int i = 0; i < 4; ++i)
#pragma unroll
            for (int j = 0; j < 4; ++j)
#pragma unroll
            for (int r = 0; r < 4; ++r) s_acc = fmaf(D[i][j][r], D[i][j][r], s_acc);
        }

        lds_fence();   // WAR: prior plane readers retired
        // ---- store W' = 0.5*(c1*I + c3*X^2), transposed (== W' by symmetry) ----
#pragma unroll
        for (int i = 0; i < 4; ++i)
#pragma unroll
        for (int j = 0; j < 4; ++j) {
            f32x4 v;
#pragma unroll
            for (int r = 0; r < 4; ++r) {
                v[r] = c3 * D[i][j][r];
                if (i == j && c == 4 * h4 + r) v[r] += c1;
            }
            stHL(Hhi, Hlo, three, c, h4, i, j, v);
        }
        lds_fence();   // RAW

        // ---- mm2: D = X*W' + W'*X (symmetrized in-register) ----
        zeroD(D);
#pragma unroll
        for (int S = 0; S < 2; ++S) {
            Frag wf[4];
#pragma unroll
            for (int t = 0; t < 4; ++t) {
                wf[t].hi = rdP(Hhi, c, h4, t, S);
                wf[t].lo = three ? rdP(Hlo, c, h4, t, S) : short8{0,0,0,0,0,0,0,0};
            }
#pragma unroll
            for (int i = 0; i < 4; ++i)
#pragma unroll
            for (int j = 0; j < 4; ++j) {
                if (three) {
                    D[i][j] = mfma3(xf[S][i], wf[j], D[i][j]);
                    D[i][j] = mfma3(wf[i], xf[S][j], D[i][j]);
                } else {
                    D[i][j] = mfma_bf(xf[S][i].hi, wf[j].hi, D[i][j]);
                    D[i][j] = mfma_bf(wf[i].hi, xf[S][j].hi, D[i][j]);
                }
            }
        }

        lds_fence();   // WAR: W reads retired before overwrite
        // ---- store X_new (transposed), read back fragments ----
#pragma unroll
        for (int i = 0; i < 4; ++i)
#pragma unroll
        for (int j = 0; j < 4; ++j) stHL(Hhi, Hlo, three, c, h4, i, j, D[i][j]);
        lds_fence();   // RAW
#pragma unroll
        for (int S = 0; S < 2; ++S)
#pragma unroll
        for (int t = 0; t < 4; ++t) {
            xf[S][t].hi = rdP(Hhi, c, h4, t, S);
            xf[S][t].lo = three ? rdP(Hlo, c, h4, t, S) : short8{0,0,0,0,0,0,0,0};
        }
    }
    // xf = frags of S = sign(B)

    // ---- validation: S^2 ~ I elementwise @0.015 ----
    bool bad = false;
    zeroD(D);
#pragma unroll
    for (int S = 0; S < 2; ++S)
#pragma unroll
    for (int i = 0; i < 4; ++i)
#pragma unroll
    for (int j = 0; j < 4; ++j) D[i][j] = mfma3(xf[S][i], xf[S][j], D[i][j]);
#pragma unroll
    for (int i = 0; i < 4; ++i)
#pragma unroll
    for (int j = 0; j < 4; ++j)
#pragma unroll
    for (int r = 0; r < 4; ++r) {
        const float expect = (i == j && c == 4 * h4 + r) ? 1.f : 0.f;
        bad |= fabsf(D[i][j][r] - expect) > 0.015f;
    }

    // ---- epilogue: D = B*S + S*B (symmetrized double product) ----
    zeroD(D);
#pragma unroll
    for (int S = 0; S < 2; ++S) {
        Frag b4[4];
#pragma unroll
        for (int t = 0; t < 4; ++t) {
            float e[8]; load_row8(src, c, h4, t, S, e); b4[t] = pack3(e);
        }
#pragma unroll
        for (int i = 0; i < 4; ++i)
#pragma unroll
        for (int j = 0; j < 4; ++j) {
            D[i][j] = mfma3(b4[i], xf[S][j], D[i][j]);
            D[i][j] = mfma3(xf[S][i], b4[j], D[i][j]);
        }
    }

    // out = 0.25*(BS+SB) + 0.5*B + eps*I
#pragma unroll
    for (int i = 0; i < 4; ++i)
#pragma unroll
    for (int j = 0; j < 4; ++j)
#pragma unroll
    for (int r = 0; r < 4; ++r) {
        const int p = 16 * i + 4 * h4 + r;
        const int q = 16 * j + c;
        const float bval = src[p * 64 + q] - ((p == q) ? EPS_ : 0.f);
        dst[p * 64 + q] = 0.25f * D[i][j][r] + 0.5f * bval + ((p == q) ? EPS_ : 0.f);
    }

    const unsigned long long bb = __ballot(bad);
    if (lane == 0) flags[mat] = (bb != 0ull) ? 1 : 0;
}

// ------------------------ fp32 fallback (known good) ------------------------
constexpr int FB_LD = 68;

__device__ __forceinline__ void fb_mm64(const float* __restrict__ A,
                                        const float* __restrict__ Bm,
                                        int ti, int tj, float acc[4][4]) {
#pragma unroll
    for (int r = 0; r < 4; ++r)
#pragma unroll
        for (int cc = 0; cc < 4; ++cc) acc[r][cc] = 0.f;
#pragma unroll 4
    for (int k = 0; k < 64; ++k) {
        const float4 a = *reinterpret_cast<const float4*>(&A [k * FB_LD + 4 * ti]);
        const float4 b = *reinterpret_cast<const float4*>(&Bm[k * FB_LD + 4 * tj]);
        const float ar[4] = {a.x, a.y, a.z, a.w};
        const float br[4] = {b.x, b.y, b.z, b.w};
#pragma unroll
        for (int r = 0; r < 4; ++r)
#pragma unroll
            for (int cc = 0; cc < 4; ++cc)
                acc[r][cc] = fmaf(ar[r], br[cc], acc[r][cc]);
    }
}

__global__ __launch_bounds__(256) void reeig_fb(const float* __restrict__ in,
                                                float* __restrict__ out,
                                                const int* __restrict__ flags) {
    if (flags && flags[blockIdx.x] == 0) return;

    __shared__ __align__(16) float Bs[64 * FB_LD];
    __shared__ __align__(16) float Xs[64 * FB_LD];
    __shared__ __align__(16) float Ws[64 * FB_LD];
    __shared__ float red[4];

    const int tid = threadIdx.x;
    const int tj  = tid & 15;
    const int ti  = tid >> 4;
    const size_t base = (size_t)blockIdx.x * 4096;
    const float* __restrict__ src = in + base;
    float* __restrict__ dst = out + base;

    float4 v4[4];
    float frob = 0.f;
#pragma unroll
    for (int q = 0; q < 4; ++q) {
        const int idx4 = tid + 256 * q;
        const int lin  = idx4 << 2;
        const int r    = lin >> 6;
        const int c    = lin & 63;
        float4 v = reinterpret_cast<const float4*>(src)[idx4];
        const int d = r - c;
        v.x -= (d == 0) ? EPS_ : 0.f;
        v.y -= (d == 1) ? EPS_ : 0.f;
        v.z -= (d == 2) ? EPS_ : 0.f;
        v.w -= (d == 3) ? EPS_ : 0.f;
        v4[q] = v;
        frob += v.x * v.x + v.y * v.y + v.z * v.z + v.w * v.w;
        *reinterpret_cast<float4*>(&Bs[r * FB_LD + c]) = v;
    }
#pragma unroll
    for (int off = 32; off > 0; off >>= 1) frob += __shfl_down(frob, off);
    if ((tid & 63) == 0) red[tid >> 6] = frob;
    __syncthreads();
    const float tot = red[0] + red[1] + red[2] + red[3];
    const float inv = (tot > 0.f) ? rsqrtf(tot) : 0.f;

#pragma unroll
    for (int q = 0; q < 4; ++q) {
        const int idx4 = tid + 256 * q;
        const int lin  = idx4 << 2;
        const int r    = lin >> 6;
        const int c    = lin & 63;
        float4 v = v4[q];
        v.x *= inv; v.y *= inv; v.z *= inv; v.w *= inv;
        *reinterpret_cast<float4*>(&Xs[r * FB_LD + c]) = v;
    }
    __syncthreads();

    float acc[4][4];
    for (int it = 0; it < 14; ++it) {
        const bool  g  = (it < 9);
        const float c1 = g ? 2.25f    : 1.5f;
        const float c3 = g ? -1.6875f : -0.5f;

        fb_mm64(Xs, Xs, ti, tj, acc);
#pragma unroll
        for (int r = 0; r < 4; ++r) {
            const int i = 4 * ti + r;
            float4 w;
            w.x = c3 * acc[r][0] + ((i == 4 * tj + 0) ? c1 : 0.f);
            w.y = c3 * acc[r][1] + ((i == 4 * tj + 1) ? c1 : 0.f);
            w.z = c3 * acc[r][2] + ((i == 4 * tj + 2) ? c1 : 0.f);
            w.w = c3 * acc[r][3] + ((i == 4 * tj + 3) ? c1 : 0.f);
            *reinterpret_cast<float4*>(&Ws[i * FB_LD + 4 * tj]) = w;
        }
        __syncthreads();

        fb_mm64(Xs, Ws, ti, tj, acc);
        __syncthreads();
#pragma unroll
        for (int r = 0; r < 4; ++r) {
            const int i = 4 * ti + r;
            float4 x;
            x.x = acc[r][0]; x.y = acc[r][1]; x.z = acc[r][2]; x.w = acc[r][3];
            *reinterpret_cast<float4*>(&Xs[i * FB_LD + 4 * tj]) = x;
        }
        __syncthreads();
    }

    fb_mm64(Bs, Xs, ti, tj, acc);
#pragma unroll
    for (int r = 0; r < 4; ++r) {
        const int i = 4 * ti + r;
        float4 o;
        o.x = 0.5f * (acc[r][0] + Bs[i * FB_LD + 4 * tj + 0]) + ((i == 4 * tj + 0) ? EPS_ : 0.f);
        o.y = 0.5f * (acc[r][1] + Bs[i * FB_LD + 4 * tj + 1]) + ((i == 4 * tj + 1) ? EPS_ : 0.f);
        o.z = 0.5f * (acc[r][2] + Bs[i * FB_LD + 4 * tj + 2]) + ((i == 4 * tj + 2) ? EPS_ : 0.f);
        o.w = 0.5f * (acc[r][3] + Bs[i * FB_LD + 4 * tj + 3]) + ((i == 4 * tj + 3) ? EPS_ : 0.f);
        *reinterpret_cast<float4*>(&dst[i * 64 + 4 * tj]) = o;
    }
}

extern "C" void kernel_launch(void* const* d_in, const int* in_sizes, int n_in,
                              void* d_out, int out_size, void* d_ws, size_t ws_size,
                              hipStream_t stream) {
    const float* X = (const float*)d_in[0];
    float* O = (float*)d_out;
    const int nmat = in_sizes[0] / 4096;   // 8192
    if (ws_size >= (size_t)nmat * sizeof(int)) {
        int* flags = (int*)d_ws;
        reeig_mx<<<nmat / 4, 256, 0, stream>>>(X, O, flags);
        reeig_fb<<<nmat, 256, 0, stream>>>(X, O, flags);
    } else {
        reeig_fb<<<nmat, 256, 0, stream>>>(X, O, nullptr);
    }
}